// Round 2
// baseline (931.275 us; speedup 1.0000x reference)
//
#include <hip/hip_runtime.h>

typedef int v4i __attribute__((ext_vector_type(4)));

#define M_DIM 4096
#define N_DIM 11008
#define K_DIM 4096
#define KP    (K_DIM / 2)   // packed int32 elements per row (one byte each)

// Compress 4 packed bytes (one per int32, values 0..255) into a dword, then
// sign-extend all low nibbles and all high nibbles branch-free (SWAR).
// Nibble v in [0,15]: signed = v | 0xF0 when bit3 set; (m & 0x08080808)*30
// turns each set bit3 into 0xF0 in its byte with no cross-byte carry.
__device__ __forceinline__ void unpack_group(int4 p, unsigned &slo, unsigned &shi) {
    unsigned c = ((unsigned)p.x & 0xFFu)
               | (((unsigned)p.y & 0xFFu) << 8)
               | (((unsigned)p.z & 0xFFu) << 16)
               | (((unsigned)p.w & 0xFFu) << 24);
    slo = (c & 0x0F0F0F0Fu) | ((c & 0x08080808u) * 30u);
    unsigned d = c >> 4;
    shi = (d & 0x0F0F0F0Fu) | ((d & 0x08080808u) * 30u);
}

// ---------------------------------------------------------------------------
// Fused unpack + GEMM: C[m,n] = (sum_k A4[m,k]*B4[n,k]) * sx[m] * sw[n]
// 128x128 tile, BK=64, 256 threads = 4 waves (2x2), each wave 64x64 via 4x4
// tiles of mfma_i32_16x16x64_i8. LDS fragment-ordered: chunk c = tile*64+lane,
// 16 B/chunk -> ds_read_b128 lane-linear. k within a chunk is permuted
// (lo-nibbles then hi-nibbles per 4-byte group) identically for A and B, so
// the dot product is unchanged.
// ---------------------------------------------------------------------------
__global__ __launch_bounds__(256) void gemm_i4_kernel(
    const int* __restrict__ Aq, const int* __restrict__ Bq,
    const float* __restrict__ sx, const float* __restrict__ sw,
    float* __restrict__ out)
{
    __shared__ v4i smem[1024];                 // 16 KB: A chunks [0,512), B [512,1024)
    unsigned char* smemA = (unsigned char*)smem;
    unsigned char* smemB = smemA + 8192;

    const int t    = threadIdx.x;
    const int lane = t & 63;
    const int w    = t >> 6;
    const int wm   = w >> 1;
    const int wn   = w & 1;
    const int rowBase = blockIdx.y * 128;
    const int colBase = blockIdx.x * 128;

    // Thread t stages chunks {t, t+256} of A and B.
    // chunk c: row = (c>>6)*16 + (c&15), k-quad q = (c>>4)&3 (16 k's = 8 packed bytes)
    const int c0 = t, c1 = t + 256;
    const int r0 = (c0 >> 6) * 16 + (c0 & 15);
    const int r1 = (c1 >> 6) * 16 + (c1 & 15);
    const int q0 = (c0 >> 4) & 3;
    const int q1 = (c1 >> 4) & 3;

    const int* gA0 = Aq + (size_t)(rowBase + r0) * KP + q0 * 8;
    const int* gA1 = Aq + (size_t)(rowBase + r1) * KP + q1 * 8;
    const int* gB0 = Bq + (size_t)(colBase + r0) * KP + q0 * 8;
    const int* gB1 = Bq + (size_t)(colBase + r1) * KP + q1 * 8;

    v4i* lA0 = (v4i*)(smemA + c0 * 16);
    v4i* lA1 = (v4i*)(smemA + c1 * 16);
    v4i* lB0 = (v4i*)(smemB + c0 * 16);
    v4i* lB1 = (v4i*)(smemB + c1 * 16);

    v4i acc[4][4] = {};

    for (int kb = 0; kb < K_DIM; kb += 64) {
        const int kp = kb >> 1;                // packed offset for this K-block
        int4 a00 = *(const int4*)(gA0 + kp);
        int4 a01 = *(const int4*)(gA0 + kp + 4);
        int4 a10 = *(const int4*)(gA1 + kp);
        int4 a11 = *(const int4*)(gA1 + kp + 4);
        int4 b00 = *(const int4*)(gB0 + kp);
        int4 b01 = *(const int4*)(gB0 + kp + 4);
        int4 b10 = *(const int4*)(gB1 + kp);
        int4 b11 = *(const int4*)(gB1 + kp + 4);

        __syncthreads();   // previous iteration's ds_reads complete

        unsigned u0, u1, u2, u3;
        unpack_group(a00, u0, u1); unpack_group(a01, u2, u3);
        *lA0 = (v4i){(int)u0, (int)u1, (int)u2, (int)u3};
        unpack_group(a10, u0, u1); unpack_group(a11, u2, u3);
        *lA1 = (v4i){(int)u0, (int)u1, (int)u2, (int)u3};
        unpack_group(b00, u0, u1); unpack_group(b01, u2, u3);
        *lB0 = (v4i){(int)u0, (int)u1, (int)u2, (int)u3};
        unpack_group(b10, u0, u1); unpack_group(b11, u2, u3);
        *lB1 = (v4i){(int)u0, (int)u1, (int)u2, (int)u3};

        __syncthreads();   // staging visible to all

        v4i af[4], bf[4];
        #pragma unroll
        for (int mt = 0; mt < 4; ++mt)
            af[mt] = *((const v4i*)(smemA + ((wm * 4 + mt) * 64 + lane) * 16));
        #pragma unroll
        for (int nt = 0; nt < 4; ++nt)
            bf[nt] = *((const v4i*)(smemB + ((wn * 4 + nt) * 64 + lane) * 16));

        #pragma unroll
        for (int mt = 0; mt < 4; ++mt)
            #pragma unroll
            for (int nt = 0; nt < 4; ++nt)
                acc[mt][nt] = __builtin_amdgcn_mfma_i32_16x16x64_i8(
                    af[mt], bf[nt], acc[mt][nt], 0, 0, 0);
    }

    // Epilogue. C/D layout (16x16): col = lane&15, row = (lane>>4)*4 + reg.
    const int ccol = lane & 15;
    const int crow = (lane >> 4) * 4;

    float xs[4][4];
    #pragma unroll
    for (int mt = 0; mt < 4; ++mt)
        #pragma unroll
        for (int r = 0; r < 4; ++r)
            xs[mt][r] = sx[rowBase + wm * 64 + mt * 16 + crow + r];

    #pragma unroll
    for (int nt = 0; nt < 4; ++nt) {
        const int gn = colBase + wn * 64 + nt * 16 + ccol;
        const float wsc = sw[gn];
        #pragma unroll
        for (int mt = 0; mt < 4; ++mt) {
            const int gm = rowBase + wm * 64 + mt * 16 + crow;
            #pragma unroll
            for (int r = 0; r < 4; ++r) {
                float v = (float)acc[mt][nt][r] * xs[mt][r] * wsc;
                out[(size_t)(gm + r) * N_DIM + gn] = v;
            }
        }
    }
}

extern "C" void kernel_launch(void* const* d_in, const int* in_sizes, int n_in,
                              void* d_out, int out_size, void* d_ws, size_t ws_size,
                              hipStream_t stream) {
    (void)in_sizes; (void)n_in; (void)out_size; (void)d_ws; (void)ws_size;
    const int*   x_q = (const int*)d_in[0];
    const float* sx  = (const float*)d_in[1];
    const int*   w_q = (const int*)d_in[2];
    const float* sw  = (const float*)d_in[3];
    float*       out = (float*)d_out;

    dim3 grid(N_DIM / 128, M_DIM / 128);   // 86 x 32, exact
    gemm_i4_kernel<<<grid, 256, 0, stream>>>(x_q, w_q, sx, sw, out);
}

// Round 3
// 634.047 us; speedup vs baseline: 1.4688x; 1.4688x over previous
//
#include <hip/hip_runtime.h>

typedef int v4i __attribute__((ext_vector_type(4)));

#define M_DIM 4096
#define N_DIM 11008
#define K_DIM 4096
#define KP    (K_DIM / 2)   // packed int32 elements per row (one byte each)

// ---------------------------------------------------------------------------
// SWAR sign-extend helpers
// ---------------------------------------------------------------------------
__device__ __forceinline__ unsigned pack2(int p) {
    int lo = (p << 28) >> 28;   // sign-extended low nibble
    int hi = (p << 24) >> 28;   // sign-extended high nibble
    return (unsigned)(lo & 0xFF) | ((unsigned)(hi & 0xFF) << 8);
}

__device__ __forceinline__ void unpack_group(int4 p, unsigned &slo, unsigned &shi) {
    unsigned c = ((unsigned)p.x & 0xFFu)
               | (((unsigned)p.y & 0xFFu) << 8)
               | (((unsigned)p.z & 0xFFu) << 16)
               | (((unsigned)p.w & 0xFFu) << 24);
    slo = (c & 0x0F0F0F0Fu) | ((c & 0x08080808u) * 30u);
    unsigned d = c >> 4;
    shi = (d & 0x0F0F0F0Fu) | ((d & 0x08080808u) * 30u);
}

// ---------------------------------------------------------------------------
// Pass 1: int32 (one byte/elem) -> signed int8, k-natural order
// (out[2j] = lo nibble, out[2j+1] = hi nibble). 16B load -> 8B store.
// ---------------------------------------------------------------------------
__global__ __launch_bounds__(256) void unpack_i4_kernel(
    const int* __restrict__ in, uint2* __restrict__ out, int n4)
{
    int idx = blockIdx.x * blockDim.x + threadIdx.x;
    if (idx >= n4) return;
    int4 v = ((const int4*)in)[idx];
    unsigned d0 = pack2(v.x) | (pack2(v.y) << 16);
    unsigned d1 = pack2(v.z) | (pack2(v.w) << 16);
    out[idx] = make_uint2(d0, d1);
}

// ---------------------------------------------------------------------------
// Pass 2: GEMM from int8.  C[m,n] = (sum_k A8[m,k]*B8[n,k]) * sx[m] * sw[n]
// 128x128 tile, BK=64, 256 threads = 4 waves (2x2), each wave 64x64 via 4x4
// tiles of mfma_i32_16x16x64_i8.  LDS fragment-ordered: chunk c = tile*64 +
// lane, 16 B/chunk -> global_load_lds dest = wave-uniform base + lane*16 (OK)
// and ds_read_b128 lane-linear (conflict-free).  Compute core identical to
// the validated round-2 kernel.
// ---------------------------------------------------------------------------
__global__ __launch_bounds__(256) void gemm_i8_kernel(
    const unsigned char* __restrict__ A8, const unsigned char* __restrict__ B8,
    const float* __restrict__ sx, const float* __restrict__ sw,
    float* __restrict__ out)
{
    __shared__ v4i smem[1024];                 // 16 KB: A chunks [0,512), B [512,1024)
    unsigned char* smemA = (unsigned char*)smem;
    unsigned char* smemB = smemA + 8192;

    const int t    = threadIdx.x;
    const int lane = t & 63;
    const int w    = t >> 6;
    const int wm   = w >> 1;
    const int wn   = w & 1;
    const int rowBase = blockIdx.y * 128;
    const int colBase = blockIdx.x * 128;

    // Thread t stages chunks {t, t+256} of A and of B.
    // chunk c: row = (c>>6)*16 + (c&15), k-quad q = (c>>4)&3 (16 k's = 16 B)
    const int c0 = t, c1 = t + 256;
    const int r0 = (c0 >> 6) * 16 + (c0 & 15);
    const int r1 = (c1 >> 6) * 16 + (c1 & 15);
    const int q0 = (c0 >> 4) & 3;
    const int q1 = (c1 >> 4) & 3;

    const unsigned char* gA0 = A8 + (size_t)(rowBase + r0) * K_DIM + q0 * 16;
    const unsigned char* gA1 = A8 + (size_t)(rowBase + r1) * K_DIM + q1 * 16;
    const unsigned char* gB0 = B8 + (size_t)(colBase + r0) * K_DIM + q0 * 16;
    const unsigned char* gB1 = B8 + (size_t)(colBase + r1) * K_DIM + q1 * 16;
    unsigned char* lA0 = smemA + c0 * 16;
    unsigned char* lA1 = smemA + c1 * 16;
    unsigned char* lB0 = smemB + c0 * 16;
    unsigned char* lB1 = smemB + c1 * 16;

    v4i acc[4][4] = {};

    for (int kb = 0; kb < K_DIM; kb += 64) {
        __syncthreads();   // previous iter's ds_reads done before overwrite
        __builtin_amdgcn_global_load_lds(
            (const __attribute__((address_space(1))) void*)(gA0 + kb),
            (__attribute__((address_space(3))) void*)lA0, 16, 0, 0);
        __builtin_amdgcn_global_load_lds(
            (const __attribute__((address_space(1))) void*)(gA1 + kb),
            (__attribute__((address_space(3))) void*)lA1, 16, 0, 0);
        __builtin_amdgcn_global_load_lds(
            (const __attribute__((address_space(1))) void*)(gB0 + kb),
            (__attribute__((address_space(3))) void*)lB0, 16, 0, 0);
        __builtin_amdgcn_global_load_lds(
            (const __attribute__((address_space(1))) void*)(gB1 + kb),
            (__attribute__((address_space(3))) void*)lB1, 16, 0, 0);
        __syncthreads();   // compiler drains vmcnt before s_barrier

        v4i af[4], bf[4];
        #pragma unroll
        for (int mt = 0; mt < 4; ++mt)
            af[mt] = *((const v4i*)(smemA + ((wm * 4 + mt) * 64 + lane) * 16));
        #pragma unroll
        for (int nt = 0; nt < 4; ++nt)
            bf[nt] = *((const v4i*)(smemB + ((wn * 4 + nt) * 64 + lane) * 16));

        #pragma unroll
        for (int mt = 0; mt < 4; ++mt)
            #pragma unroll
            for (int nt = 0; nt < 4; ++nt)
                acc[mt][nt] = __builtin_amdgcn_mfma_i32_16x16x64_i8(
                    af[mt], bf[nt], acc[mt][nt], 0, 0, 0);
    }

    // Epilogue. C/D layout (16x16): col = lane&15, row = (lane>>4)*4 + reg.
    const int ccol = lane & 15;
    const int crow = (lane >> 4) * 4;

    float xs[4][4];
    #pragma unroll
    for (int mt = 0; mt < 4; ++mt)
        #pragma unroll
        for (int r = 0; r < 4; ++r)
            xs[mt][r] = sx[rowBase + wm * 64 + mt * 16 + crow + r];

    #pragma unroll
    for (int nt = 0; nt < 4; ++nt) {
        const int gn = colBase + wn * 64 + nt * 16 + ccol;
        const float wsc = sw[gn];
        #pragma unroll
        for (int mt = 0; mt < 4; ++mt) {
            const int gm = rowBase + wm * 64 + mt * 16 + crow;
            #pragma unroll
            for (int r = 0; r < 4; ++r) {
                float v = (float)acc[mt][nt][r] * xs[mt][r] * wsc;
                out[(size_t)(gm + r) * N_DIM + gn] = v;
            }
        }
    }
}

// ---------------------------------------------------------------------------
// Fallback: fused unpack+GEMM (validated round-2 kernel), used only if d_ws
// is too small for the int8 copies.
// ---------------------------------------------------------------------------
__global__ __launch_bounds__(256) void gemm_i4_fused_kernel(
    const int* __restrict__ Aq, const int* __restrict__ Bq,
    const float* __restrict__ sx, const float* __restrict__ sw,
    float* __restrict__ out)
{
    __shared__ v4i smem[1024];
    unsigned char* smemA = (unsigned char*)smem;
    unsigned char* smemB = smemA + 8192;

    const int t    = threadIdx.x;
    const int lane = t & 63;
    const int w    = t >> 6;
    const int wm   = w >> 1;
    const int wn   = w & 1;
    const int rowBase = blockIdx.y * 128;
    const int colBase = blockIdx.x * 128;

    const int c0 = t, c1 = t + 256;
    const int r0 = (c0 >> 6) * 16 + (c0 & 15);
    const int r1 = (c1 >> 6) * 16 + (c1 & 15);
    const int q0 = (c0 >> 4) & 3;
    const int q1 = (c1 >> 4) & 3;

    const int* gA0 = Aq + (size_t)(rowBase + r0) * KP + q0 * 8;
    const int* gA1 = Aq + (size_t)(rowBase + r1) * KP + q1 * 8;
    const int* gB0 = Bq + (size_t)(colBase + r0) * KP + q0 * 8;
    const int* gB1 = Bq + (size_t)(colBase + r1) * KP + q1 * 8;

    v4i* lA0 = (v4i*)(smemA + c0 * 16);
    v4i* lA1 = (v4i*)(smemA + c1 * 16);
    v4i* lB0 = (v4i*)(smemB + c0 * 16);
    v4i* lB1 = (v4i*)(smemB + c1 * 16);

    v4i acc[4][4] = {};

    for (int kb = 0; kb < K_DIM; kb += 64) {
        const int kp = kb >> 1;
        int4 a00 = *(const int4*)(gA0 + kp);
        int4 a01 = *(const int4*)(gA0 + kp + 4);
        int4 a10 = *(const int4*)(gA1 + kp);
        int4 a11 = *(const int4*)(gA1 + kp + 4);
        int4 b00 = *(const int4*)(gB0 + kp);
        int4 b01 = *(const int4*)(gB0 + kp + 4);
        int4 b10 = *(const int4*)(gB1 + kp);
        int4 b11 = *(const int4*)(gB1 + kp + 4);

        __syncthreads();

        unsigned u0, u1, u2, u3;
        unpack_group(a00, u0, u1); unpack_group(a01, u2, u3);
        *lA0 = (v4i){(int)u0, (int)u1, (int)u2, (int)u3};
        unpack_group(a10, u0, u1); unpack_group(a11, u2, u3);
        *lA1 = (v4i){(int)u0, (int)u1, (int)u2, (int)u3};
        unpack_group(b00, u0, u1); unpack_group(b01, u2, u3);
        *lB0 = (v4i){(int)u0, (int)u1, (int)u2, (int)u3};
        unpack_group(b10, u0, u1); unpack_group(b11, u2, u3);
        *lB1 = (v4i){(int)u0, (int)u1, (int)u2, (int)u3};

        __syncthreads();

        v4i af[4], bf[4];
        #pragma unroll
        for (int mt = 0; mt < 4; ++mt)
            af[mt] = *((const v4i*)(smemA + ((wm * 4 + mt) * 64 + lane) * 16));
        #pragma unroll
        for (int nt = 0; nt < 4; ++nt)
            bf[nt] = *((const v4i*)(smemB + ((wn * 4 + nt) * 64 + lane) * 16));

        #pragma unroll
        for (int mt = 0; mt < 4; ++mt)
            #pragma unroll
            for (int nt = 0; nt < 4; ++nt)
                acc[mt][nt] = __builtin_amdgcn_mfma_i32_16x16x64_i8(
                    af[mt], bf[nt], acc[mt][nt], 0, 0, 0);
    }

    const int ccol = lane & 15;
    const int crow = (lane >> 4) * 4;

    float xs[4][4];
    #pragma unroll
    for (int mt = 0; mt < 4; ++mt)
        #pragma unroll
        for (int r = 0; r < 4; ++r)
            xs[mt][r] = sx[rowBase + wm * 64 + mt * 16 + crow + r];

    #pragma unroll
    for (int nt = 0; nt < 4; ++nt) {
        const int gn = colBase + wn * 64 + nt * 16 + ccol;
        const float wsc = sw[gn];
        #pragma unroll
        for (int mt = 0; mt < 4; ++mt) {
            const int gm = rowBase + wm * 64 + mt * 16 + crow;
            #pragma unroll
            for (int r = 0; r < 4; ++r) {
                float v = (float)acc[mt][nt][r] * xs[mt][r] * wsc;
                out[(size_t)(gm + r) * N_DIM + gn] = v;
            }
        }
    }
}

extern "C" void kernel_launch(void* const* d_in, const int* in_sizes, int n_in,
                              void* d_out, int out_size, void* d_ws, size_t ws_size,
                              hipStream_t stream) {
    (void)in_sizes; (void)n_in; (void)out_size;
    const int*   x_q = (const int*)d_in[0];
    const float* sx  = (const float*)d_in[1];
    const int*   w_q = (const int*)d_in[2];
    const float* sw  = (const float*)d_in[3];
    float*       out = (float*)d_out;

    dim3 grid(N_DIM / 128, M_DIM / 128);   // 86 x 32, exact

    const size_t needA = (size_t)M_DIM * K_DIM;        // 16.8 MB
    const size_t needB = (size_t)N_DIM * K_DIM;        // 45.1 MB
    if (ws_size >= needA + needB) {
        unsigned char* A8 = (unsigned char*)d_ws;
        unsigned char* B8 = A8 + needA;
        const int n4A = M_DIM * KP / 4;   // 2,097,152 (exact)
        const int n4B = N_DIM * KP / 4;   // 5,636,096 (exact)
        unpack_i4_kernel<<<n4A / 256, 256, 0, stream>>>(x_q, (uint2*)A8, n4A);
        unpack_i4_kernel<<<n4B / 256, 256, 0, stream>>>(w_q, (uint2*)B8, n4B);
        gemm_i8_kernel<<<grid, 256, 0, stream>>>(A8, B8, sx, sw, out);
    } else {
        gemm_i4_fused_kernel<<<grid, 256, 0, stream>>>(x_q, w_q, sx, sw, out);
    }
}